// Round 12
// baseline (2997.914 us; speedup 1.0000x reference)
//
#include <hip/hip_runtime.h>
#include <hip/hip_bf16.h>
#include <math.h>

#define T_STEPS 512
#define BATCH   64
#define IN_DIM  1024
#define HID     1024
#define BH_SZ   (BATCH * HID)

typedef short bf16x8 __attribute__((ext_vector_type(8)));
typedef float f32x4  __attribute__((ext_vector_type(4)));
typedef unsigned u32x4 __attribute__((ext_vector_type(4)));
typedef unsigned long long u64;

// ---- coherent (agent-scope, cache-bypassing) accessors --------------------
__device__ __forceinline__ unsigned ld_coh_u32(const unsigned* p) {
    return __hip_atomic_load(p, __ATOMIC_RELAXED, __HIP_MEMORY_SCOPE_AGENT);
}
__device__ __forceinline__ void st_coh_u32(unsigned* p, unsigned v) {
    __hip_atomic_store(p, v, __ATOMIC_RELAXED, __HIP_MEMORY_SCOPE_AGENT);
}
__device__ __forceinline__ u64 ld_coh_u64(const u64* p) {
    return __hip_atomic_load(p, __ATOMIC_RELAXED, __HIP_MEMORY_SCOPE_AGENT);
}

// ---- bf16 split helpers (RNE) ---------------------------------------------
__device__ __forceinline__ unsigned short f2bf(float x) {
    unsigned u = __builtin_bit_cast(unsigned, x);
    unsigned r = u + 0x7FFFu + ((u >> 16) & 1u);
    return (unsigned short)(r >> 16);
}
__device__ __forceinline__ float bf2f(unsigned short h) {
    unsigned u = ((unsigned)h) << 16;
    return __builtin_bit_cast(float, u);
}
__device__ __forceinline__ float fast_tanh(float x) {
    float e = __expf(2.0f * x);
    return 1.0f - 2.0f * __builtin_amdgcn_rcpf(e + 1.0f);
}

// ---------------------------------------------------------------------------
// Fused RNN kernel v12 = v10's replay-proven sync skeleton (4 barriers,
// full-grid 256-flag poll — FROZEN INVARIANT after v5/v11 races) plus:
//  (1) wave 0 skips bubble work and polls immediately after arrive;
//      waves 1-7 (448 thr) cover the x_{t+1} staging + out stores
//  (2) MFMA accumulator split into two independent chains
// LDS: Wih 32K + Hhi 32K + Hlo 32K + Xh 32K + Pred 8K = 136 KB.
// ---------------------------------------------------------------------------
__global__ __launch_bounds__(512, 1) void rnn_fused_kernel(
    const float* __restrict__ x,      // [T][B][I] raw input
    const float* __restrict__ h0,     // [B][H]
    const float* __restrict__ W_ih,   // [H][I]
    const float* __restrict__ Whh,    // [H][H]
    const float* __restrict__ b_ih,   // [H]
    const float* __restrict__ b_hh,   // [H]
    float* __restrict__ out,          // [T][B][H] h out; h_last at end
    unsigned* hcomm,                  // [2][B][H] packed bf16 hi/lo exchange
    unsigned* flags)                  // [256*32] zeroed
{
    __shared__ unsigned short Wih[16 * 1024];   // W_ih rows j0.., bf16 hi only
    __shared__ unsigned short Hhi[16 * 1024];
    __shared__ unsigned short Hlo[16 * 1024];
    __shared__ unsigned short Xh [16 * 1024];   // x_t rows b0.., bf16
    __shared__ f32x4 Pred[8][64];

    const int bid = blockIdx.x;
    const int j0 = (bid & 63) * 16;
    const int b0 = (bid >> 6) * 16;
    const int tid  = threadIdx.x;
    const int lane = tid & 63;
    const int w    = tid >> 6;        // wave 0..7 -> k-range [w*128,(w+1)*128)

    // fragment addressing
    const int frow = lane & 15;
    const int ksub = (lane >> 4) * 8;          // 0,8,16,24
    const int sw   = (frow & 7) << 3;

    // ---- prologue 1: stage W_ih rows j0..j0+15 (bf16 hi), XOR-swizzled ----
    #pragma unroll
    for (int i = 0; i < 4; i++) {
        int c = i * 512 + tid;
        int row = c >> 7;
        int k0 = (c & 127) * 8;
        const float* src = W_ih + (size_t)(j0 + row) * IN_DIM + k0;
        float4 v0 = *(const float4*)(src);
        float4 v1 = *(const float4*)(src + 4);
        float vv[8] = {v0.x, v0.y, v0.z, v0.w, v1.x, v1.y, v1.z, v1.w};
        bf16x8 hi8;
        #pragma unroll
        for (int e = 0; e < 8; e++) hi8[e] = (short)f2bf(vv[e]);
        int ofs = row * 1024 + (k0 ^ ((row & 7) << 3));
        *(bf16x8*)&Wih[ofs] = hi8;
    }

    // ---- prologue 2: stage W_hh split into Hhi/Hlo (TEMP), read frags ----
    #pragma unroll
    for (int i = 0; i < 4; i++) {
        int c = i * 512 + tid;
        int row = c >> 7;
        int k0 = (c & 127) * 8;
        const float* src = Whh + (size_t)(j0 + row) * HID + k0;
        float4 v0 = *(const float4*)(src);
        float4 v1 = *(const float4*)(src + 4);
        float vv[8] = {v0.x, v0.y, v0.z, v0.w, v1.x, v1.y, v1.z, v1.w};
        bf16x8 hi8, lo8;
        #pragma unroll
        for (int e = 0; e < 8; e++) {
            unsigned short h = f2bf(vv[e]);
            hi8[e] = (short)h;
            lo8[e] = (short)f2bf(vv[e] - bf2f(h));
        }
        int ofs = row * 1024 + (k0 ^ ((row & 7) << 3));
        *(bf16x8*)&Hhi[ofs] = hi8;
        *(bf16x8*)&Hlo[ofs] = lo8;
    }
    __syncthreads();
    bf16x8 wh[4], wl[4];                       // W_hh frags in registers
    #pragma unroll
    for (int kk = 0; kk < 4; kk++) {
        int kidx = w * 128 + kk * 32 + ksub;
        int ofs  = frow * 1024 + (kidx ^ sw);
        wh[kk] = *(const bf16x8*)&Hhi[ofs];
        wl[kk] = *(const bf16x8*)&Hlo[ofs];
    }
    __syncthreads();   // frags read -> Hhi/Hlo reusable for h staging

    // ---- prologue 3: stage x_0 into Xh ----
    #pragma unroll
    for (int i = 0; i < 4; i++) {
        int c = i * 512 + tid;
        int row = c >> 7;
        int k0 = (c & 127) * 8;
        const float* p = x + (size_t)(b0 + row) * IN_DIM + k0;   // t = 0
        float4 v0 = *(const float4*)(p);
        float4 v1 = *(const float4*)(p + 4);
        float vv[8] = {v0.x, v0.y, v0.z, v0.w, v1.x, v1.y, v1.z, v1.w};
        bf16x8 hi8;
        #pragma unroll
        for (int e = 0; e < 8; e++) hi8[e] = (short)f2bf(vv[e]);
        int ofs = row * 1024 + (k0 ^ ((row & 7) << 3));
        *(bf16x8*)&Xh[ofs] = hi8;
    }

    const int o = tid;                 // tid<256: b = o>>4, j = o&15
    const size_t out_off = (size_t)(b0 + (o >> 4)) * HID + (size_t)(j0 + (o & 15));
    float bias = 0.f;
    if (tid < 256) bias = b_ih[j0 + (o & 15)] + b_hh[j0 + (o & 15)];

    for (int t = 0; t < T_STEPS; t++) {
        // ---- stage h_{t-1} (16 rows) into Hhi/Hlo (v7 verbatim) ----
        if (t == 0) {
            #pragma unroll
            for (int i = 0; i < 4; i++) {
                int c = i * 512 + tid;
                int row = c >> 7;
                int k0 = (c & 127) * 8;
                const float* p = h0 + (size_t)(b0 + row) * HID + k0;
                float4 v0 = *(const float4*)(p);
                float4 v1 = *(const float4*)(p + 4);
                float vv[8] = {v0.x, v0.y, v0.z, v0.w, v1.x, v1.y, v1.z, v1.w};
                bf16x8 hi8, lo8;
                #pragma unroll
                for (int e = 0; e < 8; e++) {
                    unsigned short h = f2bf(vv[e]);
                    hi8[e] = (short)h;
                    lo8[e] = (short)f2bf(vv[e] - bf2f(h));
                }
                int ofs = row * 1024 + (k0 ^ ((row & 7) << 3));
                *(bf16x8*)&Hhi[ofs] = hi8;
                *(bf16x8*)&Hlo[ofs] = lo8;
            }
        } else {
            const u64* hsrc64 = (const u64*)(hcomm + (size_t)((t + 1) & 1) * BH_SZ);
            u64 pv[16];
            #pragma unroll
            for (int i = 0; i < 4; i++) {
                int c = i * 512 + tid;
                int row = c >> 7;
                int k0 = (c & 127) * 8;
                const u64* p = hsrc64 + (((size_t)(b0 + row) * HID + k0) >> 1);
                #pragma unroll
                for (int e = 0; e < 4; e++)
                    pv[i * 4 + e] = ld_coh_u64(p + e);
            }
            #pragma unroll
            for (int i = 0; i < 4; i++) {
                int c = i * 512 + tid;
                int row = c >> 7;
                int k0 = (c & 127) * 8;
                u32x4 hiu, lou;
                #pragma unroll
                for (int e = 0; e < 4; e++) {
                    u64 q = pv[i * 4 + e];
                    unsigned p0 = (unsigned)q;
                    unsigned p1 = (unsigned)(q >> 32);
                    hiu[e] = (p0 & 0xFFFFu) | (p1 << 16);
                    lou[e] = (p0 >> 16) | (p1 & 0xFFFF0000u);
                }
                int ofs = row * 1024 + (k0 ^ ((row & 7) << 3));
                *(u32x4*)&Hhi[ofs] = hiu;
                *(u32x4*)&Hlo[ofs] = lou;
            }
        }
        __syncthreads();   // sync A

        // ---- MFMA: W_hh·h (3-term, reg frags) + W_ih·x_t (1-term) ----
        {
            f32x4 acc0 = {0.f, 0.f, 0.f, 0.f};
            f32x4 acc1 = {0.f, 0.f, 0.f, 0.f};
            #pragma unroll
            for (int kk = 0; kk < 4; kk++) {
                int kidx = w * 128 + kk * 32 + ksub;
                int ofs  = frow * 1024 + (kidx ^ sw);
                bf16x8 ahi = *(const bf16x8*)&Hhi[ofs];
                bf16x8 alo = *(const bf16x8*)&Hlo[ofs];
                bf16x8 xh  = *(const bf16x8*)&Xh[ofs];
                bf16x8 wi  = *(const bf16x8*)&Wih[ofs];
                acc0 = __builtin_amdgcn_mfma_f32_16x16x32_bf16(ahi, wh[kk], acc0, 0, 0, 0);
                acc1 = __builtin_amdgcn_mfma_f32_16x16x32_bf16(ahi, wl[kk], acc1, 0, 0, 0);
                acc0 = __builtin_amdgcn_mfma_f32_16x16x32_bf16(alo, wh[kk], acc0, 0, 0, 0);
                acc1 = __builtin_amdgcn_mfma_f32_16x16x32_bf16(xh,  wi,     acc1, 0, 0, 0);
            }
            Pred[w][lane] = acc0 + acc1;
        }
        __syncthreads();   // sync B

        // ---- reduce + bias + tanh; coherent store (critical path) ----
        float hn = 0.f;
        if (tid < 256) {
            const int b = o >> 4, j = o & 15;
            const int plane = ((b >> 2) << 4) | j;
            const int pr = b & 3;
            float s = bias;
            #pragma unroll
            for (int k = 0; k < 8; k++) s += Pred[k][plane][pr];
            hn = fast_tanh(s);
            unsigned short hi = f2bf(hn);
            unsigned short lo = f2bf(hn - bf2f(hi));
            unsigned pk = (unsigned)hi | ((unsigned)lo << 16);
            st_coh_u32(hcomm + (size_t)(t & 1) * BH_SZ + out_off, pk);
        }
        __syncthreads();   // sync C: drains every thread's coherent h store

        // ---- arrive ----
        if (tid == 0) st_coh_u32(&flags[bid * 32], (unsigned)(t + 1));

        if (tid < 64) {
            // ---- wave 0: poll immediately (flags propagate while waves 1-7
            //      do the bubble work); own out store deferred past detect ----
            const unsigned target = (unsigned)(t + 1);
            for (;;) {
                int ok = 1;
                #pragma unroll
                for (int g = 0; g < 4; g++) {
                    unsigned v = ld_coh_u32(&flags[(size_t)(tid + g * 64) * 32]);
                    ok &= (v >= target) ? 1 : 0;
                }
                if (__all(ok)) break;
                __builtin_amdgcn_s_sleep(1);
            }
            out[(size_t)t * BH_SZ + out_off] = hn;       // own cell, write-only
            if (t == T_STEPS - 1)
                out[(size_t)T_STEPS * BH_SZ + out_off] = hn;
        } else {
            // ---- waves 1-7: out stores + x_{t+1} staging into Xh ----
            if (tid < 256) {
                out[(size_t)t * BH_SZ + out_off] = hn;
                if (t == T_STEPS - 1)
                    out[(size_t)T_STEPS * BH_SZ + out_off] = hn;
            }
            if (t + 1 < T_STEPS) {
                const float* xs = x + (size_t)(t + 1) * BH_SZ;   // B*I == BH_SZ
                const int tt = tid - 64;                          // 0..447
                #pragma unroll
                for (int i = 0; i < 5; i++) {
                    int c = i * 448 + tt;
                    if (c < 2048) {
                        int row = c >> 7;
                        int k0 = (c & 127) * 8;
                        const float* p = xs + (size_t)(b0 + row) * IN_DIM + k0;
                        float4 v0 = *(const float4*)(p);
                        float4 v1 = *(const float4*)(p + 4);
                        float vv[8] = {v0.x, v0.y, v0.z, v0.w,
                                       v1.x, v1.y, v1.z, v1.w};
                        bf16x8 hi8;
                        #pragma unroll
                        for (int e = 0; e < 8; e++) hi8[e] = (short)f2bf(vv[e]);
                        int ofs = row * 1024 + (k0 ^ ((row & 7) << 3));
                        *(bf16x8*)&Xh[ofs] = hi8;   // reads done at sync B
                    }
                }
            }
        }

        __syncthreads();   // sync D: poll done + Xh staged, step boundary
    }
}

// ---------------------------------------------------------------------------
extern "C" void kernel_launch(void* const* d_in, const int* in_sizes, int n_in,
                              void* d_out, int out_size, void* d_ws, size_t ws_size,
                              hipStream_t stream)
{
    const float* input  = (const float*)d_in[0];  // [T,B,I]
    const float* hidden = (const float*)d_in[1];  // [B,H]
    const float* W_ih   = (const float*)d_in[2];  // [H,I]
    const float* W_hh   = (const float*)d_in[3];  // [H,H]
    const float* b_ih   = (const float*)d_in[4];  // [H]
    const float* b_hh   = (const float*)d_in[5];  // [H]
    float* out = (float*)d_out;

    unsigned* flags = (unsigned*)d_ws;                          // 32 KB
    unsigned* hcomm = (unsigned*)((char*)d_ws + 256 * 32 * sizeof(unsigned));
    hipMemsetAsync(flags, 0, 256 * 32 * sizeof(unsigned), stream);

    rnn_fused_kernel<<<256, 512, 0, stream>>>(
        input, hidden, W_ih, W_hh, b_ih, b_hh, out, hcomm, flags);
}

// Round 13
// 2413.062 us; speedup vs baseline: 1.2424x; 1.2424x over previous
//
#include <hip/hip_runtime.h>
#include <hip/hip_bf16.h>
#include <math.h>

#define T_STEPS 512
#define BATCH   64
#define IN_DIM  1024
#define HID     1024
#define BH_SZ   (BATCH * HID)

typedef short bf16x8 __attribute__((ext_vector_type(8)));
typedef float f32x4  __attribute__((ext_vector_type(4)));
typedef unsigned u32x4 __attribute__((ext_vector_type(4)));
typedef unsigned long long u64;

// ---- coherent (agent-scope, cache-bypassing) accessors --------------------
__device__ __forceinline__ unsigned ld_coh_u32(const unsigned* p) {
    return __hip_atomic_load(p, __ATOMIC_RELAXED, __HIP_MEMORY_SCOPE_AGENT);
}
__device__ __forceinline__ void st_coh_u32(unsigned* p, unsigned v) {
    __hip_atomic_store(p, v, __ATOMIC_RELAXED, __HIP_MEMORY_SCOPE_AGENT);
}
__device__ __forceinline__ u64 ld_coh_u64(const u64* p) {
    return __hip_atomic_load(p, __ATOMIC_RELAXED, __HIP_MEMORY_SCOPE_AGENT);
}

// ---- bf16 split helpers (RNE) ---------------------------------------------
__device__ __forceinline__ unsigned short f2bf(float x) {
    unsigned u = __builtin_bit_cast(unsigned, x);
    unsigned r = u + 0x7FFFu + ((u >> 16) & 1u);
    return (unsigned short)(r >> 16);
}
__device__ __forceinline__ float bf2f(unsigned short h) {
    unsigned u = ((unsigned)h) << 16;
    return __builtin_bit_cast(float, u);
}
__device__ __forceinline__ float fast_tanh(float x) {
    float e = __expf(2.0f * x);
    return 1.0f - 2.0f * __builtin_amdgcn_rcpf(e + 1.0f);
}

// ---------------------------------------------------------------------------
// Fused RNN kernel v13 = v10's replay-proven skeleton (bubble-then-poll
// ordering restored after v12's eager-poll contention regression) plus:
//  (1) two-chain MFMA accumulator (from v12, compute-only)
//  (2) poll backoff s_sleep(4): ~8x less flag traffic vs s_sleep(1),
//      +<=0.1us detect granularity (only hit on straggler waits)
// Sync graph: 4 barriers/step + full-grid 256-flag poll — FROZEN INVARIANT
// (v5 group-local and v11 single-producer gating both raced under replay).
// LDS: Wih 32K + Hhi 32K + Hlo 32K + Xh 32K + Pred 8K = 136 KB.
// ---------------------------------------------------------------------------
__global__ __launch_bounds__(512, 1) void rnn_fused_kernel(
    const float* __restrict__ x,      // [T][B][I] raw input
    const float* __restrict__ h0,     // [B][H]
    const float* __restrict__ W_ih,   // [H][I]
    const float* __restrict__ Whh,    // [H][H]
    const float* __restrict__ b_ih,   // [H]
    const float* __restrict__ b_hh,   // [H]
    float* __restrict__ out,          // [T][B][H] h out; h_last at end
    unsigned* hcomm,                  // [2][B][H] packed bf16 hi/lo exchange
    unsigned* flags)                  // [256*32] zeroed
{
    __shared__ unsigned short Wih[16 * 1024];   // W_ih rows j0.., bf16 hi only
    __shared__ unsigned short Hhi[16 * 1024];
    __shared__ unsigned short Hlo[16 * 1024];
    __shared__ unsigned short Xh [16 * 1024];   // x_t rows b0.., bf16
    __shared__ f32x4 Pred[8][64];

    const int bid = blockIdx.x;
    const int j0 = (bid & 63) * 16;
    const int b0 = (bid >> 6) * 16;
    const int tid  = threadIdx.x;
    const int lane = tid & 63;
    const int w    = tid >> 6;        // wave 0..7 -> k-range [w*128,(w+1)*128)

    // fragment addressing
    const int frow = lane & 15;
    const int ksub = (lane >> 4) * 8;          // 0,8,16,24
    const int sw   = (frow & 7) << 3;

    // ---- prologue 1: stage W_ih rows j0..j0+15 (bf16 hi), XOR-swizzled ----
    #pragma unroll
    for (int i = 0; i < 4; i++) {
        int c = i * 512 + tid;
        int row = c >> 7;
        int k0 = (c & 127) * 8;
        const float* src = W_ih + (size_t)(j0 + row) * IN_DIM + k0;
        float4 v0 = *(const float4*)(src);
        float4 v1 = *(const float4*)(src + 4);
        float vv[8] = {v0.x, v0.y, v0.z, v0.w, v1.x, v1.y, v1.z, v1.w};
        bf16x8 hi8;
        #pragma unroll
        for (int e = 0; e < 8; e++) hi8[e] = (short)f2bf(vv[e]);
        int ofs = row * 1024 + (k0 ^ ((row & 7) << 3));
        *(bf16x8*)&Wih[ofs] = hi8;
    }

    // ---- prologue 2: stage W_hh split into Hhi/Hlo (TEMP), read frags ----
    #pragma unroll
    for (int i = 0; i < 4; i++) {
        int c = i * 512 + tid;
        int row = c >> 7;
        int k0 = (c & 127) * 8;
        const float* src = Whh + (size_t)(j0 + row) * HID + k0;
        float4 v0 = *(const float4*)(src);
        float4 v1 = *(const float4*)(src + 4);
        float vv[8] = {v0.x, v0.y, v0.z, v0.w, v1.x, v1.y, v1.z, v1.w};
        bf16x8 hi8, lo8;
        #pragma unroll
        for (int e = 0; e < 8; e++) {
            unsigned short h = f2bf(vv[e]);
            hi8[e] = (short)h;
            lo8[e] = (short)f2bf(vv[e] - bf2f(h));
        }
        int ofs = row * 1024 + (k0 ^ ((row & 7) << 3));
        *(bf16x8*)&Hhi[ofs] = hi8;
        *(bf16x8*)&Hlo[ofs] = lo8;
    }
    __syncthreads();
    bf16x8 wh[4], wl[4];                       // W_hh frags in registers
    #pragma unroll
    for (int kk = 0; kk < 4; kk++) {
        int kidx = w * 128 + kk * 32 + ksub;
        int ofs  = frow * 1024 + (kidx ^ sw);
        wh[kk] = *(const bf16x8*)&Hhi[ofs];
        wl[kk] = *(const bf16x8*)&Hlo[ofs];
    }
    __syncthreads();   // frags read -> Hhi/Hlo reusable for h staging

    // ---- prologue 3: stage x_0 into Xh ----
    #pragma unroll
    for (int i = 0; i < 4; i++) {
        int c = i * 512 + tid;
        int row = c >> 7;
        int k0 = (c & 127) * 8;
        const float* p = x + (size_t)(b0 + row) * IN_DIM + k0;   // t = 0
        float4 v0 = *(const float4*)(p);
        float4 v1 = *(const float4*)(p + 4);
        float vv[8] = {v0.x, v0.y, v0.z, v0.w, v1.x, v1.y, v1.z, v1.w};
        bf16x8 hi8;
        #pragma unroll
        for (int e = 0; e < 8; e++) hi8[e] = (short)f2bf(vv[e]);
        int ofs = row * 1024 + (k0 ^ ((row & 7) << 3));
        *(bf16x8*)&Xh[ofs] = hi8;
    }

    const int o = tid;                 // tid<256: b = o>>4, j = o&15
    const size_t out_off = (size_t)(b0 + (o >> 4)) * HID + (size_t)(j0 + (o & 15));
    float bias = 0.f;
    if (tid < 256) bias = b_ih[j0 + (o & 15)] + b_hh[j0 + (o & 15)];

    for (int t = 0; t < T_STEPS; t++) {
        // ---- stage h_{t-1} (16 rows) into Hhi/Hlo (v7 verbatim) ----
        if (t == 0) {
            #pragma unroll
            for (int i = 0; i < 4; i++) {
                int c = i * 512 + tid;
                int row = c >> 7;
                int k0 = (c & 127) * 8;
                const float* p = h0 + (size_t)(b0 + row) * HID + k0;
                float4 v0 = *(const float4*)(p);
                float4 v1 = *(const float4*)(p + 4);
                float vv[8] = {v0.x, v0.y, v0.z, v0.w, v1.x, v1.y, v1.z, v1.w};
                bf16x8 hi8, lo8;
                #pragma unroll
                for (int e = 0; e < 8; e++) {
                    unsigned short h = f2bf(vv[e]);
                    hi8[e] = (short)h;
                    lo8[e] = (short)f2bf(vv[e] - bf2f(h));
                }
                int ofs = row * 1024 + (k0 ^ ((row & 7) << 3));
                *(bf16x8*)&Hhi[ofs] = hi8;
                *(bf16x8*)&Hlo[ofs] = lo8;
            }
        } else {
            const u64* hsrc64 = (const u64*)(hcomm + (size_t)((t + 1) & 1) * BH_SZ);
            u64 pv[16];
            #pragma unroll
            for (int i = 0; i < 4; i++) {
                int c = i * 512 + tid;
                int row = c >> 7;
                int k0 = (c & 127) * 8;
                const u64* p = hsrc64 + (((size_t)(b0 + row) * HID + k0) >> 1);
                #pragma unroll
                for (int e = 0; e < 4; e++)
                    pv[i * 4 + e] = ld_coh_u64(p + e);
            }
            #pragma unroll
            for (int i = 0; i < 4; i++) {
                int c = i * 512 + tid;
                int row = c >> 7;
                int k0 = (c & 127) * 8;
                u32x4 hiu, lou;
                #pragma unroll
                for (int e = 0; e < 4; e++) {
                    u64 q = pv[i * 4 + e];
                    unsigned p0 = (unsigned)q;
                    unsigned p1 = (unsigned)(q >> 32);
                    hiu[e] = (p0 & 0xFFFFu) | (p1 << 16);
                    lou[e] = (p0 >> 16) | (p1 & 0xFFFF0000u);
                }
                int ofs = row * 1024 + (k0 ^ ((row & 7) << 3));
                *(u32x4*)&Hhi[ofs] = hiu;
                *(u32x4*)&Hlo[ofs] = lou;
            }
        }
        __syncthreads();   // sync A

        // ---- MFMA: W_hh·h (3-term, reg frags) + W_ih·x_t (1-term) ----
        {
            f32x4 acc0 = {0.f, 0.f, 0.f, 0.f};
            f32x4 acc1 = {0.f, 0.f, 0.f, 0.f};
            #pragma unroll
            for (int kk = 0; kk < 4; kk++) {
                int kidx = w * 128 + kk * 32 + ksub;
                int ofs  = frow * 1024 + (kidx ^ sw);
                bf16x8 ahi = *(const bf16x8*)&Hhi[ofs];
                bf16x8 alo = *(const bf16x8*)&Hlo[ofs];
                bf16x8 xh  = *(const bf16x8*)&Xh[ofs];
                bf16x8 wi  = *(const bf16x8*)&Wih[ofs];
                acc0 = __builtin_amdgcn_mfma_f32_16x16x32_bf16(ahi, wh[kk], acc0, 0, 0, 0);
                acc1 = __builtin_amdgcn_mfma_f32_16x16x32_bf16(ahi, wl[kk], acc1, 0, 0, 0);
                acc0 = __builtin_amdgcn_mfma_f32_16x16x32_bf16(alo, wh[kk], acc0, 0, 0, 0);
                acc1 = __builtin_amdgcn_mfma_f32_16x16x32_bf16(xh,  wi,     acc1, 0, 0, 0);
            }
            Pred[w][lane] = acc0 + acc1;
        }
        __syncthreads();   // sync B

        // ---- reduce + bias + tanh; coherent store (critical path) ----
        float hn = 0.f;
        if (tid < 256) {
            const int b = o >> 4, j = o & 15;
            const int plane = ((b >> 2) << 4) | j;
            const int pr = b & 3;
            float s = bias;
            #pragma unroll
            for (int k = 0; k < 8; k++) s += Pred[k][plane][pr];
            hn = fast_tanh(s);
            unsigned short hi = f2bf(hn);
            unsigned short lo = f2bf(hn - bf2f(hi));
            unsigned pk = (unsigned)hi | ((unsigned)lo << 16);
            st_coh_u32(hcomm + (size_t)(t & 1) * BH_SZ + out_off, pk);
        }
        __syncthreads();   // sync C: drains every thread's coherent h store

        // ---- arrive ----
        if (tid == 0) st_coh_u32(&flags[bid * 32], (unsigned)(t + 1));

        // ---- bubble work FIRST (v10 ordering): out stores + x_{t+1} ----
        if (tid < 256) {
            out[(size_t)t * BH_SZ + out_off] = hn;
            if (t == T_STEPS - 1)
                out[(size_t)T_STEPS * BH_SZ + out_off] = hn;
        }
        if (t + 1 < T_STEPS) {
            const float* xs = x + (size_t)(t + 1) * BH_SZ;   // B*I == BH_SZ
            #pragma unroll
            for (int i = 0; i < 4; i++) {
                int c = i * 512 + tid;
                int row = c >> 7;
                int k0 = (c & 127) * 8;
                const float* p = xs + (size_t)(b0 + row) * IN_DIM + k0;
                float4 v0 = *(const float4*)(p);
                float4 v1 = *(const float4*)(p + 4);
                float vv[8] = {v0.x, v0.y, v0.z, v0.w, v1.x, v1.y, v1.z, v1.w};
                bf16x8 hi8;
                #pragma unroll
                for (int e = 0; e < 8; e++) hi8[e] = (short)f2bf(vv[e]);
                int ofs = row * 1024 + (k0 ^ ((row & 7) << 3));
                *(bf16x8*)&Xh[ofs] = hi8;   // reads done at prior sync B
            }
        }

        // ---- wait: FULL grid, throttled poll (s_sleep(4) backoff) ----
        if (tid < 64) {
            const unsigned target = (unsigned)(t + 1);
            for (;;) {
                int ok = 1;
                #pragma unroll
                for (int g = 0; g < 4; g++) {
                    unsigned v = ld_coh_u32(&flags[(size_t)(tid + g * 64) * 32]);
                    ok &= (v >= target) ? 1 : 0;
                }
                if (__all(ok)) break;
                __builtin_amdgcn_s_sleep(4);
            }
        }
        __syncthreads();   // sync D
    }
}

// ---------------------------------------------------------------------------
extern "C" void kernel_launch(void* const* d_in, const int* in_sizes, int n_in,
                              void* d_out, int out_size, void* d_ws, size_t ws_size,
                              hipStream_t stream)
{
    const float* input  = (const float*)d_in[0];  // [T,B,I]
    const float* hidden = (const float*)d_in[1];  // [B,H]
    const float* W_ih   = (const float*)d_in[2];  // [H,I]
    const float* W_hh   = (const float*)d_in[3];  // [H,H]
    const float* b_ih   = (const float*)d_in[4];  // [H]
    const float* b_hh   = (const float*)d_in[5];  // [H]
    float* out = (float*)d_out;

    unsigned* flags = (unsigned*)d_ws;                          // 32 KB
    unsigned* hcomm = (unsigned*)((char*)d_ws + 256 * 32 * sizeof(unsigned));
    hipMemsetAsync(flags, 0, 256 * 32 * sizeof(unsigned), stream);

    rnn_fused_kernel<<<256, 512, 0, stream>>>(
        input, hidden, W_ih, W_hh, b_ih, b_hh, out, hcomm, flags);
}

// Round 14
// 2312.702 us; speedup vs baseline: 1.2963x; 1.0434x over previous
//
#include <hip/hip_runtime.h>
#include <hip/hip_bf16.h>
#include <math.h>

#define T_STEPS 512
#define BATCH   64
#define IN_DIM  1024
#define HID     1024
#define BH_SZ   (BATCH * HID)

typedef short bf16x8 __attribute__((ext_vector_type(8)));
typedef float f32x4  __attribute__((ext_vector_type(4)));
typedef unsigned u32x4 __attribute__((ext_vector_type(4)));
typedef unsigned long long u64;

// ---- coherent (agent-scope, cache-bypassing) accessors --------------------
__device__ __forceinline__ unsigned ld_coh_u32(const unsigned* p) {
    return __hip_atomic_load(p, __ATOMIC_RELAXED, __HIP_MEMORY_SCOPE_AGENT);
}
__device__ __forceinline__ void st_coh_u32(unsigned* p, unsigned v) {
    __hip_atomic_store(p, v, __ATOMIC_RELAXED, __HIP_MEMORY_SCOPE_AGENT);
}
__device__ __forceinline__ u64 ld_coh_u64(const u64* p) {
    return __hip_atomic_load(p, __ATOMIC_RELAXED, __HIP_MEMORY_SCOPE_AGENT);
}

// ---- bf16 split helpers (RNE) ---------------------------------------------
__device__ __forceinline__ unsigned short f2bf(float x) {
    unsigned u = __builtin_bit_cast(unsigned, x);
    unsigned r = u + 0x7FFFu + ((u >> 16) & 1u);
    return (unsigned short)(r >> 16);
}
__device__ __forceinline__ float bf2f(unsigned short h) {
    unsigned u = ((unsigned)h) << 16;
    return __builtin_bit_cast(float, u);
}
__device__ __forceinline__ float fast_tanh(float x) {
    float e = __expf(2.0f * x);
    return 1.0f - 2.0f * __builtin_amdgcn_rcpf(e + 1.0f);
}

// ---------------------------------------------------------------------------
// one-time x pre-pack: f32 -> bf16 (RNE, hi only), vectorized 8-wide
// ---------------------------------------------------------------------------
__global__ __launch_bounds__(256) void pack_x_kernel(
    const float* __restrict__ src, unsigned short* __restrict__ dst, int n8)
{
    int idx = blockIdx.x * 256 + threadIdx.x;
    int stride = gridDim.x * 256;
    for (int i = idx; i < n8; i += stride) {
        float4 a = *(const float4*)(src + (size_t)i * 8);
        float4 b = *(const float4*)(src + (size_t)i * 8 + 4);
        float vv[8] = {a.x, a.y, a.z, a.w, b.x, b.y, b.z, b.w};
        bf16x8 o;
        #pragma unroll
        for (int e = 0; e < 8; e++) o[e] = (short)f2bf(vv[e]);
        *(bf16x8*)(dst + (size_t)i * 8) = o;
    }
}

// ---------------------------------------------------------------------------
// Fused RNN kernel v14 = v13 (replay-proven skeleton: 4 barriers/step,
// full-grid 256-flag poll [FROZEN INVARIANT], bubble-then-throttled-poll,
// two-chain MFMA acc) with ONE change:
//   x staging reads pre-packed bf16 (xp16) when available -> zero VALU
//   convert in the bubble; f32 fallback path is byte-identical to v13.
// LDS: Wih 32K + Hhi 32K + Hlo 32K + Xh 32K + Pred 8K = 136 KB.
// ---------------------------------------------------------------------------
__global__ __launch_bounds__(512, 1) void rnn_fused_kernel(
    const float* __restrict__ x,      // [T][B][I] raw input (fallback)
    const unsigned short* __restrict__ xp16,  // packed bf16 x or nullptr
    const float* __restrict__ h0,     // [B][H]
    const float* __restrict__ W_ih,   // [H][I]
    const float* __restrict__ Whh,    // [H][H]
    const float* __restrict__ b_ih,   // [H]
    const float* __restrict__ b_hh,   // [H]
    float* __restrict__ out,          // [T][B][H] h out; h_last at end
    unsigned* hcomm,                  // [2][B][H] packed bf16 hi/lo exchange
    unsigned* flags)                  // [256*32] zeroed
{
    __shared__ unsigned short Wih[16 * 1024];   // W_ih rows j0.., bf16 hi only
    __shared__ unsigned short Hhi[16 * 1024];
    __shared__ unsigned short Hlo[16 * 1024];
    __shared__ unsigned short Xh [16 * 1024];   // x_t rows b0.., bf16
    __shared__ f32x4 Pred[8][64];

    const int bid = blockIdx.x;
    const int j0 = (bid & 63) * 16;
    const int b0 = (bid >> 6) * 16;
    const int tid  = threadIdx.x;
    const int lane = tid & 63;
    const int w    = tid >> 6;        // wave 0..7 -> k-range [w*128,(w+1)*128)

    // fragment addressing
    const int frow = lane & 15;
    const int ksub = (lane >> 4) * 8;          // 0,8,16,24
    const int sw   = (frow & 7) << 3;

    // ---- prologue 1: stage W_ih rows j0..j0+15 (bf16 hi), XOR-swizzled ----
    #pragma unroll
    for (int i = 0; i < 4; i++) {
        int c = i * 512 + tid;
        int row = c >> 7;
        int k0 = (c & 127) * 8;
        const float* src = W_ih + (size_t)(j0 + row) * IN_DIM + k0;
        float4 v0 = *(const float4*)(src);
        float4 v1 = *(const float4*)(src + 4);
        float vv[8] = {v0.x, v0.y, v0.z, v0.w, v1.x, v1.y, v1.z, v1.w};
        bf16x8 hi8;
        #pragma unroll
        for (int e = 0; e < 8; e++) hi8[e] = (short)f2bf(vv[e]);
        int ofs = row * 1024 + (k0 ^ ((row & 7) << 3));
        *(bf16x8*)&Wih[ofs] = hi8;
    }

    // ---- prologue 2: stage W_hh split into Hhi/Hlo (TEMP), read frags ----
    #pragma unroll
    for (int i = 0; i < 4; i++) {
        int c = i * 512 + tid;
        int row = c >> 7;
        int k0 = (c & 127) * 8;
        const float* src = Whh + (size_t)(j0 + row) * HID + k0;
        float4 v0 = *(const float4*)(src);
        float4 v1 = *(const float4*)(src + 4);
        float vv[8] = {v0.x, v0.y, v0.z, v0.w, v1.x, v1.y, v1.z, v1.w};
        bf16x8 hi8, lo8;
        #pragma unroll
        for (int e = 0; e < 8; e++) {
            unsigned short h = f2bf(vv[e]);
            hi8[e] = (short)h;
            lo8[e] = (short)f2bf(vv[e] - bf2f(h));
        }
        int ofs = row * 1024 + (k0 ^ ((row & 7) << 3));
        *(bf16x8*)&Hhi[ofs] = hi8;
        *(bf16x8*)&Hlo[ofs] = lo8;
    }
    __syncthreads();
    bf16x8 wh[4], wl[4];                       // W_hh frags in registers
    #pragma unroll
    for (int kk = 0; kk < 4; kk++) {
        int kidx = w * 128 + kk * 32 + ksub;
        int ofs  = frow * 1024 + (kidx ^ sw);
        wh[kk] = *(const bf16x8*)&Hhi[ofs];
        wl[kk] = *(const bf16x8*)&Hlo[ofs];
    }
    __syncthreads();   // frags read -> Hhi/Hlo reusable for h staging

    // ---- prologue 3: stage x_0 into Xh ----
    if (xp16) {
        #pragma unroll
        for (int i = 0; i < 4; i++) {
            int c = i * 512 + tid;
            int row = c >> 7;
            int k0 = (c & 127) * 8;
            bf16x8 hi8 = *(const bf16x8*)(xp16 + (size_t)(b0 + row) * IN_DIM + k0);
            int ofs = row * 1024 + (k0 ^ ((row & 7) << 3));
            *(bf16x8*)&Xh[ofs] = hi8;
        }
    } else {
        #pragma unroll
        for (int i = 0; i < 4; i++) {
            int c = i * 512 + tid;
            int row = c >> 7;
            int k0 = (c & 127) * 8;
            const float* p = x + (size_t)(b0 + row) * IN_DIM + k0;
            float4 v0 = *(const float4*)(p);
            float4 v1 = *(const float4*)(p + 4);
            float vv[8] = {v0.x, v0.y, v0.z, v0.w, v1.x, v1.y, v1.z, v1.w};
            bf16x8 hi8;
            #pragma unroll
            for (int e = 0; e < 8; e++) hi8[e] = (short)f2bf(vv[e]);
            int ofs = row * 1024 + (k0 ^ ((row & 7) << 3));
            *(bf16x8*)&Xh[ofs] = hi8;
        }
    }

    const int o = tid;                 // tid<256: b = o>>4, j = o&15
    const size_t out_off = (size_t)(b0 + (o >> 4)) * HID + (size_t)(j0 + (o & 15));
    float bias = 0.f;
    if (tid < 256) bias = b_ih[j0 + (o & 15)] + b_hh[j0 + (o & 15)];

    for (int t = 0; t < T_STEPS; t++) {
        // ---- stage h_{t-1} (16 rows) into Hhi/Hlo (v7 verbatim) ----
        if (t == 0) {
            #pragma unroll
            for (int i = 0; i < 4; i++) {
                int c = i * 512 + tid;
                int row = c >> 7;
                int k0 = (c & 127) * 8;
                const float* p = h0 + (size_t)(b0 + row) * HID + k0;
                float4 v0 = *(const float4*)(p);
                float4 v1 = *(const float4*)(p + 4);
                float vv[8] = {v0.x, v0.y, v0.z, v0.w, v1.x, v1.y, v1.z, v1.w};
                bf16x8 hi8, lo8;
                #pragma unroll
                for (int e = 0; e < 8; e++) {
                    unsigned short h = f2bf(vv[e]);
                    hi8[e] = (short)h;
                    lo8[e] = (short)f2bf(vv[e] - bf2f(h));
                }
                int ofs = row * 1024 + (k0 ^ ((row & 7) << 3));
                *(bf16x8*)&Hhi[ofs] = hi8;
                *(bf16x8*)&Hlo[ofs] = lo8;
            }
        } else {
            const u64* hsrc64 = (const u64*)(hcomm + (size_t)((t + 1) & 1) * BH_SZ);
            u64 pv[16];
            #pragma unroll
            for (int i = 0; i < 4; i++) {
                int c = i * 512 + tid;
                int row = c >> 7;
                int k0 = (c & 127) * 8;
                const u64* p = hsrc64 + (((size_t)(b0 + row) * HID + k0) >> 1);
                #pragma unroll
                for (int e = 0; e < 4; e++)
                    pv[i * 4 + e] = ld_coh_u64(p + e);
            }
            #pragma unroll
            for (int i = 0; i < 4; i++) {
                int c = i * 512 + tid;
                int row = c >> 7;
                int k0 = (c & 127) * 8;
                u32x4 hiu, lou;
                #pragma unroll
                for (int e = 0; e < 4; e++) {
                    u64 q = pv[i * 4 + e];
                    unsigned p0 = (unsigned)q;
                    unsigned p1 = (unsigned)(q >> 32);
                    hiu[e] = (p0 & 0xFFFFu) | (p1 << 16);
                    lou[e] = (p0 >> 16) | (p1 & 0xFFFF0000u);
                }
                int ofs = row * 1024 + (k0 ^ ((row & 7) << 3));
                *(u32x4*)&Hhi[ofs] = hiu;
                *(u32x4*)&Hlo[ofs] = lou;
            }
        }
        __syncthreads();   // sync A

        // ---- MFMA: W_hh·h (3-term, reg frags) + W_ih·x_t (1-term) ----
        {
            f32x4 acc0 = {0.f, 0.f, 0.f, 0.f};
            f32x4 acc1 = {0.f, 0.f, 0.f, 0.f};
            #pragma unroll
            for (int kk = 0; kk < 4; kk++) {
                int kidx = w * 128 + kk * 32 + ksub;
                int ofs  = frow * 1024 + (kidx ^ sw);
                bf16x8 ahi = *(const bf16x8*)&Hhi[ofs];
                bf16x8 alo = *(const bf16x8*)&Hlo[ofs];
                bf16x8 xh  = *(const bf16x8*)&Xh[ofs];
                bf16x8 wi  = *(const bf16x8*)&Wih[ofs];
                acc0 = __builtin_amdgcn_mfma_f32_16x16x32_bf16(ahi, wh[kk], acc0, 0, 0, 0);
                acc1 = __builtin_amdgcn_mfma_f32_16x16x32_bf16(ahi, wl[kk], acc1, 0, 0, 0);
                acc0 = __builtin_amdgcn_mfma_f32_16x16x32_bf16(alo, wh[kk], acc0, 0, 0, 0);
                acc1 = __builtin_amdgcn_mfma_f32_16x16x32_bf16(xh,  wi,     acc1, 0, 0, 0);
            }
            Pred[w][lane] = acc0 + acc1;
        }
        __syncthreads();   // sync B

        // ---- reduce + bias + tanh; coherent store (critical path) ----
        float hn = 0.f;
        if (tid < 256) {
            const int b = o >> 4, j = o & 15;
            const int plane = ((b >> 2) << 4) | j;
            const int pr = b & 3;
            float s = bias;
            #pragma unroll
            for (int k = 0; k < 8; k++) s += Pred[k][plane][pr];
            hn = fast_tanh(s);
            unsigned short hi = f2bf(hn);
            unsigned short lo = f2bf(hn - bf2f(hi));
            unsigned pk = (unsigned)hi | ((unsigned)lo << 16);
            st_coh_u32(hcomm + (size_t)(t & 1) * BH_SZ + out_off, pk);
        }
        __syncthreads();   // sync C: drains every thread's coherent h store

        // ---- arrive ----
        if (tid == 0) st_coh_u32(&flags[bid * 32], (unsigned)(t + 1));

        // ---- bubble work FIRST (v10/v13 ordering): out stores + x_{t+1} ----
        if (tid < 256) {
            out[(size_t)t * BH_SZ + out_off] = hn;
            if (t == T_STEPS - 1)
                out[(size_t)T_STEPS * BH_SZ + out_off] = hn;
        }
        if (t + 1 < T_STEPS) {
            if (xp16) {
                const unsigned short* xs = xp16 + (size_t)(t + 1) * BH_SZ;
                #pragma unroll
                for (int i = 0; i < 4; i++) {
                    int c = i * 512 + tid;
                    int row = c >> 7;
                    int k0 = (c & 127) * 8;
                    bf16x8 hi8 = *(const bf16x8*)(xs + (size_t)(b0 + row) * IN_DIM + k0);
                    int ofs = row * 1024 + (k0 ^ ((row & 7) << 3));
                    *(bf16x8*)&Xh[ofs] = hi8;   // reads done at prior sync B
                }
            } else {
                const float* xs = x + (size_t)(t + 1) * BH_SZ;   // B*I == BH_SZ
                #pragma unroll
                for (int i = 0; i < 4; i++) {
                    int c = i * 512 + tid;
                    int row = c >> 7;
                    int k0 = (c & 127) * 8;
                    const float* p = xs + (size_t)(b0 + row) * IN_DIM + k0;
                    float4 v0 = *(const float4*)(p);
                    float4 v1 = *(const float4*)(p + 4);
                    float vv[8] = {v0.x, v0.y, v0.z, v0.w, v1.x, v1.y, v1.z, v1.w};
                    bf16x8 hi8;
                    #pragma unroll
                    for (int e = 0; e < 8; e++) hi8[e] = (short)f2bf(vv[e]);
                    int ofs = row * 1024 + (k0 ^ ((row & 7) << 3));
                    *(bf16x8*)&Xh[ofs] = hi8;
                }
            }
        }

        // ---- wait: FULL grid, throttled poll (s_sleep(4) backoff) ----
        if (tid < 64) {
            const unsigned target = (unsigned)(t + 1);
            for (;;) {
                int ok = 1;
                #pragma unroll
                for (int g = 0; g < 4; g++) {
                    unsigned v = ld_coh_u32(&flags[(size_t)(tid + g * 64) * 32]);
                    ok &= (v >= target) ? 1 : 0;
                }
                if (__all(ok)) break;
                __builtin_amdgcn_s_sleep(4);
            }
        }
        __syncthreads();   // sync D
    }
}

// ---------------------------------------------------------------------------
extern "C" void kernel_launch(void* const* d_in, const int* in_sizes, int n_in,
                              void* d_out, int out_size, void* d_ws, size_t ws_size,
                              hipStream_t stream)
{
    const float* input  = (const float*)d_in[0];  // [T,B,I]
    const float* hidden = (const float*)d_in[1];  // [B,H]
    const float* W_ih   = (const float*)d_in[2];  // [H,I]
    const float* W_hh   = (const float*)d_in[3];  // [H,H]
    const float* b_ih   = (const float*)d_in[4];  // [H]
    const float* b_hh   = (const float*)d_in[5];  // [H]
    float* out = (float*)d_out;

    unsigned* flags = (unsigned*)d_ws;                          // 32 KB
    unsigned* hcomm = (unsigned*)((char*)d_ws + 256 * 32 * sizeof(unsigned));
    hipMemsetAsync(flags, 0, 256 * 32 * sizeof(unsigned), stream);

    // optional pre-packed x (bf16) at ws offset 1 MB, if workspace allows
    const size_t xpk_off  = (size_t)1 << 20;
    const size_t xpk_size = (size_t)T_STEPS * BH_SZ * sizeof(unsigned short);
    const unsigned short* xp16 = nullptr;
    if (ws_size >= xpk_off + xpk_size) {
        unsigned short* xp = (unsigned short*)((char*)d_ws + xpk_off);
        pack_x_kernel<<<2048, 256, 0, stream>>>(input, xp,
                                                (T_STEPS * BATCH * IN_DIM) / 8);
        xp16 = xp;
    }

    rnn_fused_kernel<<<256, 512, 0, stream>>>(
        input, xp16, hidden, W_ih, W_hh, b_ih, b_hh, out, hcomm, flags);
}